// Round 3
// baseline (6298.701 us; speedup 1.0000x reference)
//
#include <hip/hip_runtime.h>

#define HID 128
#define ASPITCH 132   // 128 + 4 pad: keeps 16B alignment, breaks power-of-2 bank stride
#define BM 32         // gemm row tile: 1563 blocks -> ~6 blocks/CU (occupancy was the limiter)

// ---------------- CSR build ----------------

__global__ __launch_bounds__(256) void k_count(const int* __restrict__ ei, int E,
                                               int* __restrict__ deg) {
    int e = blockIdx.x * 256 + threadIdx.x;
    if (e < E) atomicAdd(&deg[ei[E + e]], 1);   // row 1 of edge_index = dst
}

__global__ __launch_bounds__(256) void k_scan1(const int* __restrict__ deg,
                                               int* __restrict__ rowptr,
                                               int* __restrict__ partial, int n) {
    __shared__ int s[256];
    int tid = threadIdx.x;
    int i = blockIdx.x * 256 + tid;
    int v = (i < n) ? deg[i] : 0;
    s[tid] = v;
    __syncthreads();
    for (int off = 1; off < 256; off <<= 1) {
        int t = (tid >= off) ? s[tid - off] : 0;
        __syncthreads();
        s[tid] += t;
        __syncthreads();
    }
    if (i < n) rowptr[i] = s[tid] - v;           // block-local exclusive
    if (tid == 255) partial[blockIdx.x] = s[255];
}

__global__ __launch_bounds__(256) void k_scan2(int* __restrict__ partial, int nb) {
    __shared__ int s[256];
    int tid = threadIdx.x;
    int v = (tid < nb) ? partial[tid] : 0;
    s[tid] = v;
    __syncthreads();
    for (int off = 1; off < 256; off <<= 1) {
        int t = (tid >= off) ? s[tid - off] : 0;
        __syncthreads();
        s[tid] += t;
        __syncthreads();
    }
    if (tid < nb) partial[tid] = s[tid] - v;     // exclusive over block sums
}

__global__ __launch_bounds__(256) void k_scan3(int* __restrict__ rowptr,
                                               const int* __restrict__ partial,
                                               int n, int E) {
    int i = blockIdx.x * 256 + threadIdx.x;
    if (i < n) rowptr[i] += partial[blockIdx.x];
    if (i == 0) rowptr[n] = E;
}

__global__ __launch_bounds__(256) void k_dis(const int* __restrict__ deg,
                                             float* __restrict__ dis, int n) {
    int i = blockIdx.x * 256 + threadIdx.x;
    if (i < n) dis[i] = 1.0f / sqrtf((float)(deg[i] + 1));  // +1 self-loop
}

__global__ __launch_bounds__(256) void k_fill(const int* __restrict__ ei, int E,
                                              const int* __restrict__ rowptr,
                                              int* __restrict__ cursor,
                                              int* __restrict__ col) {
    int e = blockIdx.x * 256 + threadIdx.x;
    if (e < E) {
        int d = ei[E + e];
        int p = atomicAdd(&cursor[d], 1);
        col[rowptr[d] + p] = ei[e];
    }
}

// ---------------- per-layer kernels ----------------

// T[i,:] = dis[i] * (A[i,:] @ W)
// 256 threads; tile BM=32 rows x 128 cols; thread: 2 rows x 8 cols.
// W loads double-buffered (load k+4 while FMA k) to hide L1/L2 latency.
__global__ __launch_bounds__(256) void k_gemm(const float* __restrict__ A,
                                              const float* __restrict__ W,
                                              const float* __restrict__ dis,
                                              float* __restrict__ T, int n) {
    __shared__ float As[BM * ASPITCH];   // ~16.9 KiB
    int r0 = blockIdx.x * BM;
    int tid = threadIdx.x;
    int rows = n - r0; if (rows > BM) rows = BM;
    {
        const float4* A4 = (const float4*)(A + (size_t)r0 * HID);
        int tot = rows * (HID / 4);
        for (int i = tid; i < tot; i += 256) {
            int row = i >> 5, c = (i & 31) << 2;
            *(float4*)&As[row * ASPITCH + c] = A4[i];
        }
    }
    __syncthreads();

    int tx = tid & 15, ty = tid >> 4;        // 16 col-groups x 16 row-groups
    int c0 = tx * 8, rr0 = ty * 2;

    float acc[2][8];
    #pragma unroll
    for (int r = 0; r < 2; ++r)
        #pragma unroll
        for (int c = 0; c < 8; ++c) acc[r][c] = 0.0f;

    // current / next W k-quad buffers
    float4 wc[8], wn[8];
    #pragma unroll
    for (int i = 0; i < 4; ++i) {
        wc[2 * i]     = *(const float4*)&W[i * HID + c0];
        wc[2 * i + 1] = *(const float4*)&W[i * HID + c0 + 4];
    }

    #pragma unroll
    for (int k = 0; k < HID; k += 4) {
        if (k + 4 < HID) {
            #pragma unroll
            for (int i = 0; i < 4; ++i) {
                wn[2 * i]     = *(const float4*)&W[(k + 4 + i) * HID + c0];
                wn[2 * i + 1] = *(const float4*)&W[(k + 4 + i) * HID + c0 + 4];
            }
        }
        #pragma unroll
        for (int r = 0; r < 2; ++r) {
            float4 a = *(const float4*)&As[(rr0 + r) * ASPITCH + k];
            const float ax[4] = {a.x, a.y, a.z, a.w};
            #pragma unroll
            for (int i = 0; i < 4; ++i) {
                float4 wlo = wc[2 * i], whi = wc[2 * i + 1];
                acc[r][0] = fmaf(ax[i], wlo.x, acc[r][0]);
                acc[r][1] = fmaf(ax[i], wlo.y, acc[r][1]);
                acc[r][2] = fmaf(ax[i], wlo.z, acc[r][2]);
                acc[r][3] = fmaf(ax[i], wlo.w, acc[r][3]);
                acc[r][4] = fmaf(ax[i], whi.x, acc[r][4]);
                acc[r][5] = fmaf(ax[i], whi.y, acc[r][5]);
                acc[r][6] = fmaf(ax[i], whi.z, acc[r][6]);
                acc[r][7] = fmaf(ax[i], whi.w, acc[r][7]);
            }
        }
        #pragma unroll
        for (int i = 0; i < 8; ++i) wc[i] = wn[i];
    }

    #pragma unroll
    for (int r = 0; r < 2; ++r) {
        int row = rr0 + r;
        if (row < rows) {
            float d = dis[r0 + row];
            float4 o0 = make_float4(acc[r][0] * d, acc[r][1] * d, acc[r][2] * d, acc[r][3] * d);
            float4 o1 = make_float4(acc[r][4] * d, acc[r][5] * d, acc[r][6] * d, acc[r][7] * d);
            *(float4*)&T[(size_t)(r0 + row) * HID + c0] = o0;
            *(float4*)&T[(size_t)(r0 + row) * HID + c0 + 4] = o1;
        }
    }
}

// H[i,:] = relu(dis[i] * (T[i,:] + sum_{j in adj(i)} T[j,:]) + b)
// half-wave (32 lanes x float4) per node; cascade unroll 8/2/1 -> 8 gathers in flight.
__global__ __launch_bounds__(256) void k_agg(const float* __restrict__ T,
                                             const int* __restrict__ rowptr,
                                             const int* __restrict__ col,
                                             const float* __restrict__ dis,
                                             const float* __restrict__ b,
                                             float* __restrict__ H, int n) {
    int node = (blockIdx.x * 256 + threadIdx.x) >> 5;
    int lane = threadIdx.x & 31;
    if (node >= n) return;
    size_t foff = (size_t)(lane * 4);
    size_t base = (size_t)node * HID + foff;
    float4 acc = *(const float4*)&T[base];          // self-loop (pre-scaled by dis[j])
    float4 acc2 = make_float4(0.f, 0.f, 0.f, 0.f);
    int e = rowptr[node], e1 = rowptr[node + 1];
    for (; e + 8 <= e1; e += 8) {
        int j0 = col[e + 0];
        int j1 = col[e + 1];
        int j2 = col[e + 2];
        int j3 = col[e + 3];
        int j4 = col[e + 4];
        int j5 = col[e + 5];
        int j6 = col[e + 6];
        int j7 = col[e + 7];
        float4 v0 = *(const float4*)&T[(size_t)j0 * HID + foff];
        float4 v1 = *(const float4*)&T[(size_t)j1 * HID + foff];
        float4 v2 = *(const float4*)&T[(size_t)j2 * HID + foff];
        float4 v3 = *(const float4*)&T[(size_t)j3 * HID + foff];
        float4 v4 = *(const float4*)&T[(size_t)j4 * HID + foff];
        float4 v5 = *(const float4*)&T[(size_t)j5 * HID + foff];
        float4 v6 = *(const float4*)&T[(size_t)j6 * HID + foff];
        float4 v7 = *(const float4*)&T[(size_t)j7 * HID + foff];
        acc.x  += (v0.x + v1.x) + (v2.x + v3.x);
        acc.y  += (v0.y + v1.y) + (v2.y + v3.y);
        acc.z  += (v0.z + v1.z) + (v2.z + v3.z);
        acc.w  += (v0.w + v1.w) + (v2.w + v3.w);
        acc2.x += (v4.x + v5.x) + (v6.x + v7.x);
        acc2.y += (v4.y + v5.y) + (v6.y + v7.y);
        acc2.z += (v4.z + v5.z) + (v6.z + v7.z);
        acc2.w += (v4.w + v5.w) + (v6.w + v7.w);
    }
    for (; e + 2 <= e1; e += 2) {
        int j0 = col[e + 0];
        int j1 = col[e + 1];
        float4 v0 = *(const float4*)&T[(size_t)j0 * HID + foff];
        float4 v1 = *(const float4*)&T[(size_t)j1 * HID + foff];
        acc.x  += v0.x; acc.y  += v0.y; acc.z  += v0.z; acc.w  += v0.w;
        acc2.x += v1.x; acc2.y += v1.y; acc2.z += v1.z; acc2.w += v1.w;
    }
    if (e < e1) {
        int j = col[e];
        float4 v = *(const float4*)&T[(size_t)j * HID + foff];
        acc.x += v.x; acc.y += v.y; acc.z += v.z; acc.w += v.w;
    }
    acc.x += acc2.x; acc.y += acc2.y; acc.z += acc2.z; acc.w += acc2.w;
    float d = dis[node];
    float4 bb = *(const float4*)&b[lane * 4];
    float4 o;
    o.x = fmaxf(fmaf(d, acc.x, bb.x), 0.0f);
    o.y = fmaxf(fmaf(d, acc.y, bb.y), 0.0f);
    o.z = fmaxf(fmaf(d, acc.z, bb.z), 0.0f);
    o.w = fmaxf(fmaf(d, acc.w, bb.w), 0.0f);
    *(float4*)&H[base] = o;
}

// out[i] = H[i,:] @ lin_w + lin_b    half-wave per node
__global__ __launch_bounds__(256) void k_final(const float* __restrict__ H,
                                               const float* __restrict__ w,
                                               const float* __restrict__ lb,
                                               float* __restrict__ out, int n) {
    int node = (blockIdx.x * 256 + threadIdx.x) >> 5;
    int lane = threadIdx.x & 31;
    if (node >= n) return;
    float4 h = *(const float4*)&H[(size_t)node * HID + lane * 4];
    float4 ww = *(const float4*)&w[lane * 4];
    float s = h.x * ww.x + h.y * ww.y + h.z * ww.z + h.w * ww.w;
    #pragma unroll
    for (int o = 16; o > 0; o >>= 1) s += __shfl_down(s, o, 64);  // stays within half
    if (lane == 0) out[node] = s + lb[0];
}

// ---------------- launch ----------------

extern "C" void kernel_launch(void* const* d_in, const int* in_sizes, int n_in,
                              void* d_out, int out_size, void* d_ws, size_t ws_size,
                              hipStream_t stream) {
    const float* x     = (const float*)d_in[0];
    const int*   ei    = (const int*)d_in[1];
    const float* Ws    = (const float*)d_in[2];
    const float* bs    = (const float*)d_in[3];
    const float* lin_w = (const float*)d_in[4];
    const float* lin_b = (const float*)d_in[5];
    float* out = (float*)d_out;

    int n = in_sizes[0] / HID;           // 50000
    int E = in_sizes[1] / 2;             // 600000
    int L = in_sizes[2] / (HID * HID);   // 7

    char* ws = (char*)d_ws;
    size_t off = 0;
    auto alloc = [&](size_t bytes) -> void* {
        void* p = ws + off;
        off += (bytes + 255) & ~(size_t)255;
        return p;
    };
    int*   deg     = (int*)alloc((size_t)n * 4);
    int*   cursor  = (int*)alloc((size_t)n * 4);
    int*   rowptr  = (int*)alloc((size_t)(n + 1) * 4);
    int*   partial = (int*)alloc(1024);
    float* dis     = (float*)alloc((size_t)n * 4);
    int*   col     = (int*)alloc((size_t)E * 4);
    float* hbuf    = (float*)alloc((size_t)n * HID * 4);
    float* tbuf    = (float*)alloc((size_t)n * HID * 4);
    (void)ws_size;

    hipMemsetAsync(deg, 0, (size_t)n * 4, stream);
    hipMemsetAsync(cursor, 0, (size_t)n * 4, stream);

    int eb = (E + 255) / 256;
    int nb = (n + 255) / 256;
    k_count<<<eb, 256, 0, stream>>>(ei, E, deg);
    k_scan1<<<nb, 256, 0, stream>>>(deg, rowptr, partial, n);
    k_scan2<<<1, 256, 0, stream>>>(partial, nb);
    k_scan3<<<nb, 256, 0, stream>>>(rowptr, partial, n, E);
    k_dis<<<nb, 256, 0, stream>>>(deg, dis, n);
    k_fill<<<eb, 256, 0, stream>>>(ei, E, rowptr, cursor, col);

    const float* hin = x;
    int gb = (n + BM - 1) / BM;  // 1563 GEMM blocks
    int hb = (n + 7) / 8;        // 8 half-waves (=nodes) per 256-thread block
    for (int l = 0; l < L; ++l) {
        k_gemm<<<gb, 256, 0, stream>>>(hin, Ws + (size_t)l * HID * HID, dis, tbuf, n);
        k_agg<<<hb, 256, 0, stream>>>(tbuf, rowptr, col, dis, bs + (size_t)l * HID, hbuf, n);
        hin = hbuf;
    }
    k_final<<<hb, 256, 0, stream>>>(hbuf, lin_w, lin_b, out, n);
}

// Round 4
// 808.539 us; speedup vs baseline: 7.7902x; 7.7902x over previous
//
#include <hip/hip_runtime.h>

#define HID 128
#define ASPITCH 132   // 128 + 4 pad: keeps 16B alignment, breaks power-of-2 bank stride
#define BM 32         // 1563 blocks -> ~6 blocks/CU (round-2 limiter was grid-bound occupancy)

// ---------------- CSR build ----------------

__global__ __launch_bounds__(256) void k_count(const int* __restrict__ ei, int E,
                                               int* __restrict__ deg) {
    int e = blockIdx.x * 256 + threadIdx.x;
    if (e < E) atomicAdd(&deg[ei[E + e]], 1);   // row 1 of edge_index = dst
}

__global__ __launch_bounds__(256) void k_scan1(const int* __restrict__ deg,
                                               int* __restrict__ rowptr,
                                               int* __restrict__ partial, int n) {
    __shared__ int s[256];
    int tid = threadIdx.x;
    int i = blockIdx.x * 256 + tid;
    int v = (i < n) ? deg[i] : 0;
    s[tid] = v;
    __syncthreads();
    for (int off = 1; off < 256; off <<= 1) {
        int t = (tid >= off) ? s[tid - off] : 0;
        __syncthreads();
        s[tid] += t;
        __syncthreads();
    }
    if (i < n) rowptr[i] = s[tid] - v;           // block-local exclusive
    if (tid == 255) partial[blockIdx.x] = s[255];
}

__global__ __launch_bounds__(256) void k_scan2(int* __restrict__ partial, int nb) {
    __shared__ int s[256];
    int tid = threadIdx.x;
    int v = (tid < nb) ? partial[tid] : 0;
    s[tid] = v;
    __syncthreads();
    for (int off = 1; off < 256; off <<= 1) {
        int t = (tid >= off) ? s[tid - off] : 0;
        __syncthreads();
        s[tid] += t;
        __syncthreads();
    }
    if (tid < nb) partial[tid] = s[tid] - v;     // exclusive over block sums
}

__global__ __launch_bounds__(256) void k_scan3(int* __restrict__ rowptr,
                                               const int* __restrict__ partial,
                                               int n, int E) {
    int i = blockIdx.x * 256 + threadIdx.x;
    if (i < n) rowptr[i] += partial[blockIdx.x];
    if (i == 0) rowptr[n] = E;
}

__global__ __launch_bounds__(256) void k_dis(const int* __restrict__ deg,
                                             float* __restrict__ dis, int n) {
    int i = blockIdx.x * 256 + threadIdx.x;
    if (i < n) dis[i] = 1.0f / sqrtf((float)(deg[i] + 1));  // +1 self-loop
}

__global__ __launch_bounds__(256) void k_fill(const int* __restrict__ ei, int E,
                                              const int* __restrict__ rowptr,
                                              int* __restrict__ cursor,
                                              int* __restrict__ col) {
    int e = blockIdx.x * 256 + threadIdx.x;
    if (e < E) {
        int d = ei[E + e];
        int p = atomicAdd(&cursor[d], 1);
        col[rowptr[d] + p] = ei[e];
    }
}

// ---------------- per-layer kernels ----------------

// T[i,:] = dis[i] * (A[i,:] @ W)
// 256 threads; tile BM=32 rows x 128 cols; thread: 2 rows x 8 cols.
// Round-2 inner loop verbatim (VGPR ~52, no spill): rolled k-loop, inline W loads.
__global__ __launch_bounds__(256) void k_gemm(const float* __restrict__ A,
                                              const float* __restrict__ W,
                                              const float* __restrict__ dis,
                                              float* __restrict__ T, int n) {
    __shared__ float As[BM * ASPITCH];   // ~16.9 KiB
    int r0 = blockIdx.x * BM;
    int tid = threadIdx.x;
    int rows = n - r0; if (rows > BM) rows = BM;
    {
        const float4* A4 = (const float4*)(A + (size_t)r0 * HID);
        int tot = rows * (HID / 4);
        for (int i = tid; i < tot; i += 256) {
            int row = i >> 5, c = (i & 31) << 2;
            *(float4*)&As[row * ASPITCH + c] = A4[i];
        }
    }
    __syncthreads();

    int tx = tid & 15, ty = tid >> 4;        // 16 col-groups x 16 row-groups
    int c0 = tx * 8, rr0 = ty * 2;

    float acc[2][8];
    #pragma unroll
    for (int r = 0; r < 2; ++r)
        #pragma unroll
        for (int c = 0; c < 8; ++c) acc[r][c] = 0.0f;

    for (int k = 0; k < HID; k += 4) {   // rolled: keeps VGPR low, no spill
        float wf[4][8];
        #pragma unroll
        for (int i = 0; i < 4; ++i) {
            float4 w0 = *(const float4*)&W[(k + i) * HID + c0];
            float4 w1 = *(const float4*)&W[(k + i) * HID + c0 + 4];
            wf[i][0] = w0.x; wf[i][1] = w0.y; wf[i][2] = w0.z; wf[i][3] = w0.w;
            wf[i][4] = w1.x; wf[i][5] = w1.y; wf[i][6] = w1.z; wf[i][7] = w1.w;
        }
        #pragma unroll
        for (int r = 0; r < 2; ++r) {
            float4 a = *(const float4*)&As[(rr0 + r) * ASPITCH + k];
            #pragma unroll
            for (int c = 0; c < 8; ++c) {
                float t = acc[r][c];
                t = fmaf(a.x, wf[0][c], t);
                t = fmaf(a.y, wf[1][c], t);
                t = fmaf(a.z, wf[2][c], t);
                t = fmaf(a.w, wf[3][c], t);
                acc[r][c] = t;
            }
        }
    }

    #pragma unroll
    for (int r = 0; r < 2; ++r) {
        int row = rr0 + r;
        if (row < rows) {
            float d = dis[r0 + row];
            float4 o0 = make_float4(acc[r][0] * d, acc[r][1] * d, acc[r][2] * d, acc[r][3] * d);
            float4 o1 = make_float4(acc[r][4] * d, acc[r][5] * d, acc[r][6] * d, acc[r][7] * d);
            *(float4*)&T[(size_t)(r0 + row) * HID + c0] = o0;
            *(float4*)&T[(size_t)(r0 + row) * HID + c0 + 4] = o1;
        }
    }
}

// H[i,:] = relu(dis[i] * (T[i,:] + sum_{j in adj(i)} T[j,:]) + b)
// half-wave (32 lanes x float4) per node; cascade unroll 8/2/1 -> 8 gathers in flight.
__global__ __launch_bounds__(256) void k_agg(const float* __restrict__ T,
                                             const int* __restrict__ rowptr,
                                             const int* __restrict__ col,
                                             const float* __restrict__ dis,
                                             const float* __restrict__ b,
                                             float* __restrict__ H, int n) {
    int node = (blockIdx.x * 256 + threadIdx.x) >> 5;
    int lane = threadIdx.x & 31;
    if (node >= n) return;
    size_t foff = (size_t)(lane * 4);
    size_t base = (size_t)node * HID + foff;
    float4 acc = *(const float4*)&T[base];          // self-loop (pre-scaled by dis[j])
    float4 acc2 = make_float4(0.f, 0.f, 0.f, 0.f);
    int e = rowptr[node], e1 = rowptr[node + 1];
    for (; e + 8 <= e1; e += 8) {
        int j0 = col[e + 0];
        int j1 = col[e + 1];
        int j2 = col[e + 2];
        int j3 = col[e + 3];
        int j4 = col[e + 4];
        int j5 = col[e + 5];
        int j6 = col[e + 6];
        int j7 = col[e + 7];
        float4 v0 = *(const float4*)&T[(size_t)j0 * HID + foff];
        float4 v1 = *(const float4*)&T[(size_t)j1 * HID + foff];
        float4 v2 = *(const float4*)&T[(size_t)j2 * HID + foff];
        float4 v3 = *(const float4*)&T[(size_t)j3 * HID + foff];
        float4 v4 = *(const float4*)&T[(size_t)j4 * HID + foff];
        float4 v5 = *(const float4*)&T[(size_t)j5 * HID + foff];
        float4 v6 = *(const float4*)&T[(size_t)j6 * HID + foff];
        float4 v7 = *(const float4*)&T[(size_t)j7 * HID + foff];
        acc.x  += (v0.x + v1.x) + (v2.x + v3.x);
        acc.y  += (v0.y + v1.y) + (v2.y + v3.y);
        acc.z  += (v0.z + v1.z) + (v2.z + v3.z);
        acc.w  += (v0.w + v1.w) + (v2.w + v3.w);
        acc2.x += (v4.x + v5.x) + (v6.x + v7.x);
        acc2.y += (v4.y + v5.y) + (v6.y + v7.y);
        acc2.z += (v4.z + v5.z) + (v6.z + v7.z);
        acc2.w += (v4.w + v5.w) + (v6.w + v7.w);
    }
    for (; e + 2 <= e1; e += 2) {
        int j0 = col[e + 0];
        int j1 = col[e + 1];
        float4 v0 = *(const float4*)&T[(size_t)j0 * HID + foff];
        float4 v1 = *(const float4*)&T[(size_t)j1 * HID + foff];
        acc.x  += v0.x; acc.y  += v0.y; acc.z  += v0.z; acc.w  += v0.w;
        acc2.x += v1.x; acc2.y += v1.y; acc2.z += v1.z; acc2.w += v1.w;
    }
    if (e < e1) {
        int j = col[e];
        float4 v = *(const float4*)&T[(size_t)j * HID + foff];
        acc.x += v.x; acc.y += v.y; acc.z += v.z; acc.w += v.w;
    }
    acc.x += acc2.x; acc.y += acc2.y; acc.z += acc2.z; acc.w += acc2.w;
    float d = dis[node];
    float4 bb = *(const float4*)&b[lane * 4];
    float4 o;
    o.x = fmaxf(fmaf(d, acc.x, bb.x), 0.0f);
    o.y = fmaxf(fmaf(d, acc.y, bb.y), 0.0f);
    o.z = fmaxf(fmaf(d, acc.z, bb.z), 0.0f);
    o.w = fmaxf(fmaf(d, acc.w, bb.w), 0.0f);
    *(float4*)&H[base] = o;
}

// out[i] = H[i,:] @ lin_w + lin_b    half-wave per node
__global__ __launch_bounds__(256) void k_final(const float* __restrict__ H,
                                               const float* __restrict__ w,
                                               const float* __restrict__ lb,
                                               float* __restrict__ out, int n) {
    int node = (blockIdx.x * 256 + threadIdx.x) >> 5;
    int lane = threadIdx.x & 31;
    if (node >= n) return;
    float4 h = *(const float4*)&H[(size_t)node * HID + lane * 4];
    float4 ww = *(const float4*)&w[lane * 4];
    float s = h.x * ww.x + h.y * ww.y + h.z * ww.z + h.w * ww.w;
    #pragma unroll
    for (int o = 16; o > 0; o >>= 1) s += __shfl_down(s, o, 64);  // stays within half
    if (lane == 0) out[node] = s + lb[0];
}

// ---------------- launch ----------------

extern "C" void kernel_launch(void* const* d_in, const int* in_sizes, int n_in,
                              void* d_out, int out_size, void* d_ws, size_t ws_size,
                              hipStream_t stream) {
    const float* x     = (const float*)d_in[0];
    const int*   ei    = (const int*)d_in[1];
    const float* Ws    = (const float*)d_in[2];
    const float* bs    = (const float*)d_in[3];
    const float* lin_w = (const float*)d_in[4];
    const float* lin_b = (const float*)d_in[5];
    float* out = (float*)d_out;

    int n = in_sizes[0] / HID;           // 50000
    int E = in_sizes[1] / 2;             // 600000
    int L = in_sizes[2] / (HID * HID);   // 7

    char* ws = (char*)d_ws;
    size_t off = 0;
    auto alloc = [&](size_t bytes) -> void* {
        void* p = ws + off;
        off += (bytes + 255) & ~(size_t)255;
        return p;
    };
    int*   deg     = (int*)alloc((size_t)n * 4);
    int*   cursor  = (int*)alloc((size_t)n * 4);
    int*   rowptr  = (int*)alloc((size_t)(n + 1) * 4);
    int*   partial = (int*)alloc(1024);
    float* dis     = (float*)alloc((size_t)n * 4);
    int*   col     = (int*)alloc((size_t)E * 4);
    float* hbuf    = (float*)alloc((size_t)n * HID * 4);
    float* tbuf    = (float*)alloc((size_t)n * HID * 4);
    (void)ws_size;

    hipMemsetAsync(deg, 0, (size_t)n * 4, stream);
    hipMemsetAsync(cursor, 0, (size_t)n * 4, stream);

    int eb = (E + 255) / 256;
    int nb = (n + 255) / 256;
    k_count<<<eb, 256, 0, stream>>>(ei, E, deg);
    k_scan1<<<nb, 256, 0, stream>>>(deg, rowptr, partial, n);
    k_scan2<<<1, 256, 0, stream>>>(partial, nb);
    k_scan3<<<nb, 256, 0, stream>>>(rowptr, partial, n, E);
    k_dis<<<nb, 256, 0, stream>>>(deg, dis, n);
    k_fill<<<eb, 256, 0, stream>>>(ei, E, rowptr, cursor, col);

    const float* hin = x;
    int gb = (n + BM - 1) / BM;  // 1563 GEMM blocks
    int hb = (n + 7) / 8;        // 8 half-waves (=nodes) per 256-thread block
    for (int l = 0; l < L; ++l) {
        k_gemm<<<gb, 256, 0, stream>>>(hin, Ws + (size_t)l * HID * HID, dis, tbuf, n);
        k_agg<<<hb, 256, 0, stream>>>(tbuf, rowptr, col, dis, bs + (size_t)l * HID, hbuf, n);
        hin = hbuf;
    }
    k_final<<<hb, 256, 0, stream>>>(hbuf, lin_w, lin_b, out, n);
}

// Round 5
// 622.426 us; speedup vs baseline: 10.1196x; 1.2990x over previous
//
#include <hip/hip_runtime.h>

#define HID 128
#define ASPITCH 132   // 128 + 4 pad: keeps 16B alignment, breaks power-of-2 bank stride
#define BM 64         // round-2 geometry: 782 blocks, 8r x 4c thread tile (best W amortization)

// ---------------- CSR build ----------------

__global__ __launch_bounds__(256) void k_count(const int* __restrict__ ei, int E,
                                               int* __restrict__ deg) {
    int e = blockIdx.x * 256 + threadIdx.x;
    if (e < E) atomicAdd(&deg[ei[E + e]], 1);   // row 1 of edge_index = dst
}

__global__ __launch_bounds__(256) void k_scan1(const int* __restrict__ deg,
                                               int* __restrict__ rowptr,
                                               int* __restrict__ partial, int n) {
    __shared__ int s[256];
    int tid = threadIdx.x;
    int i = blockIdx.x * 256 + tid;
    int v = (i < n) ? deg[i] : 0;
    s[tid] = v;
    __syncthreads();
    for (int off = 1; off < 256; off <<= 1) {
        int t = (tid >= off) ? s[tid - off] : 0;
        __syncthreads();
        s[tid] += t;
        __syncthreads();
    }
    if (i < n) rowptr[i] = s[tid] - v;           // block-local exclusive
    if (tid == 255) partial[blockIdx.x] = s[255];
}

__global__ __launch_bounds__(256) void k_scan2(int* __restrict__ partial, int nb) {
    __shared__ int s[256];
    int tid = threadIdx.x;
    int v = (tid < nb) ? partial[tid] : 0;
    s[tid] = v;
    __syncthreads();
    for (int off = 1; off < 256; off <<= 1) {
        int t = (tid >= off) ? s[tid - off] : 0;
        __syncthreads();
        s[tid] += t;
        __syncthreads();
    }
    if (tid < nb) partial[tid] = s[tid] - v;     // exclusive over block sums
}

__global__ __launch_bounds__(256) void k_scan3(int* __restrict__ rowptr,
                                               const int* __restrict__ partial,
                                               int n, int E) {
    int i = blockIdx.x * 256 + threadIdx.x;
    if (i < n) rowptr[i] += partial[blockIdx.x];
    if (i == 0) rowptr[n] = E;
}

__global__ __launch_bounds__(256) void k_dis(const int* __restrict__ deg,
                                             float* __restrict__ dis, int n) {
    int i = blockIdx.x * 256 + threadIdx.x;
    if (i < n) dis[i] = 1.0f / sqrtf((float)(deg[i] + 1));  // +1 self-loop
}

__global__ __launch_bounds__(256) void k_fill(const int* __restrict__ ei, int E,
                                              const int* __restrict__ rowptr,
                                              int* __restrict__ cursor,
                                              int* __restrict__ col) {
    int e = blockIdx.x * 256 + threadIdx.x;
    if (e < E) {
        int d = ei[E + e];
        int p = atomicAdd(&cursor[d], 1);
        col[rowptr[d] + p] = ei[e];
    }
}

// ---------------- per-layer kernels ----------------

// T[i,:] = dis[i] * (A[i,:] @ W)
// 256 threads; tile BM=64 rows x 128 cols; thread tile 8 rows x 4 cols (round-2 geometry).
// W k-quads double-buffered in named registers (wa*/wb*), k-loop rolled (#pragma unroll 1)
// so the prefetch cannot trigger a round-3-style unroll/VGPR explosion.
__global__ __launch_bounds__(256, 3) void k_gemm(const float* __restrict__ A,
                                                 const float* __restrict__ W,
                                                 const float* __restrict__ dis,
                                                 float* __restrict__ T, int n) {
    __shared__ float As[BM * ASPITCH];   // ~33 KiB
    int r0 = blockIdx.x * BM;
    int tid = threadIdx.x;
    int rows = n - r0; if (rows > BM) rows = BM;
    {
        const float4* A4 = (const float4*)(A + (size_t)r0 * HID);
        int tot = rows * (HID / 4);
        for (int i = tid; i < tot; i += 256) {
            int row = i >> 5, c = (i & 31) << 2;
            *(float4*)&As[row * ASPITCH + c] = A4[i];
        }
    }
    __syncthreads();

    int tx = tid & 31, ty = tid >> 5;    // 32 col-groups x 8 row-groups
    int rr0 = ty * 8;
    const float4* W4 = (const float4*)W; // row stride 32 float4; this thread's col = tx

    float acc[8][4];
    #pragma unroll
    for (int r = 0; r < 8; ++r) { acc[r][0]=0.f; acc[r][1]=0.f; acc[r][2]=0.f; acc[r][3]=0.f; }

    // preload k-quad 0 into buffer A
    float4 wa0 = W4[0 * 32 + tx];
    float4 wa1 = W4[1 * 32 + tx];
    float4 wa2 = W4[2 * 32 + tx];
    float4 wa3 = W4[3 * 32 + tx];
    float4 wb0, wb1, wb2, wb3;

    #pragma unroll 1
    for (int k = 0; k < HID; k += 8) {
        // prefetch quad k+4 into B while FMAing quad k from A
        wb0 = W4[(k + 4) * 32 + tx];
        wb1 = W4[(k + 5) * 32 + tx];
        wb2 = W4[(k + 6) * 32 + tx];
        wb3 = W4[(k + 7) * 32 + tx];
        #pragma unroll
        for (int r = 0; r < 8; ++r) {
            float4 a = *(const float4*)&As[(rr0 + r) * ASPITCH + k];
            acc[r][0] = fmaf(a.x, wa0.x, acc[r][0]);
            acc[r][1] = fmaf(a.x, wa0.y, acc[r][1]);
            acc[r][2] = fmaf(a.x, wa0.z, acc[r][2]);
            acc[r][3] = fmaf(a.x, wa0.w, acc[r][3]);
            acc[r][0] = fmaf(a.y, wa1.x, acc[r][0]);
            acc[r][1] = fmaf(a.y, wa1.y, acc[r][1]);
            acc[r][2] = fmaf(a.y, wa1.z, acc[r][2]);
            acc[r][3] = fmaf(a.y, wa1.w, acc[r][3]);
            acc[r][0] = fmaf(a.z, wa2.x, acc[r][0]);
            acc[r][1] = fmaf(a.z, wa2.y, acc[r][1]);
            acc[r][2] = fmaf(a.z, wa2.z, acc[r][2]);
            acc[r][3] = fmaf(a.z, wa2.w, acc[r][3]);
            acc[r][0] = fmaf(a.w, wa3.x, acc[r][0]);
            acc[r][1] = fmaf(a.w, wa3.y, acc[r][1]);
            acc[r][2] = fmaf(a.w, wa3.z, acc[r][2]);
            acc[r][3] = fmaf(a.w, wa3.w, acc[r][3]);
        }
        // prefetch quad k+8 into A (guarded, uniform branch) while FMAing quad k+4 from B
        if (k + 8 < HID) {
            wa0 = W4[(k + 8)  * 32 + tx];
            wa1 = W4[(k + 9)  * 32 + tx];
            wa2 = W4[(k + 10) * 32 + tx];
            wa3 = W4[(k + 11) * 32 + tx];
        }
        #pragma unroll
        for (int r = 0; r < 8; ++r) {
            float4 a = *(const float4*)&As[(rr0 + r) * ASPITCH + k + 4];
            acc[r][0] = fmaf(a.x, wb0.x, acc[r][0]);
            acc[r][1] = fmaf(a.x, wb0.y, acc[r][1]);
            acc[r][2] = fmaf(a.x, wb0.z, acc[r][2]);
            acc[r][3] = fmaf(a.x, wb0.w, acc[r][3]);
            acc[r][0] = fmaf(a.y, wb1.x, acc[r][0]);
            acc[r][1] = fmaf(a.y, wb1.y, acc[r][1]);
            acc[r][2] = fmaf(a.y, wb1.z, acc[r][2]);
            acc[r][3] = fmaf(a.y, wb1.w, acc[r][3]);
            acc[r][0] = fmaf(a.z, wb2.x, acc[r][0]);
            acc[r][1] = fmaf(a.z, wb2.y, acc[r][1]);
            acc[r][2] = fmaf(a.z, wb2.z, acc[r][2]);
            acc[r][3] = fmaf(a.z, wb2.w, acc[r][3]);
            acc[r][0] = fmaf(a.w, wb3.x, acc[r][0]);
            acc[r][1] = fmaf(a.w, wb3.y, acc[r][1]);
            acc[r][2] = fmaf(a.w, wb3.z, acc[r][2]);
            acc[r][3] = fmaf(a.w, wb3.w, acc[r][3]);
        }
    }

    int c0 = tx * 4;
    #pragma unroll
    for (int r = 0; r < 8; ++r) {
        int row = rr0 + r;
        if (row < rows) {
            float d = dis[r0 + row];
            float4 o = make_float4(acc[r][0] * d, acc[r][1] * d, acc[r][2] * d, acc[r][3] * d);
            *(float4*)&T[(size_t)(r0 + row) * HID + c0] = o;
        }
    }
}

// H[i,:] = relu(dis[i] * (T[i,:] + sum_{j in adj(i)} T[j,:]) + b)
// half-wave (32 lanes x float4) per node; cascade unroll 8/2/1 -> 8 gathers in flight.
__global__ __launch_bounds__(256) void k_agg(const float* __restrict__ T,
                                             const int* __restrict__ rowptr,
                                             const int* __restrict__ col,
                                             const float* __restrict__ dis,
                                             const float* __restrict__ b,
                                             float* __restrict__ H, int n) {
    int node = (blockIdx.x * 256 + threadIdx.x) >> 5;
    int lane = threadIdx.x & 31;
    if (node >= n) return;
    size_t foff = (size_t)(lane * 4);
    size_t base = (size_t)node * HID + foff;
    float4 acc = *(const float4*)&T[base];          // self-loop (pre-scaled by dis[j])
    float4 acc2 = make_float4(0.f, 0.f, 0.f, 0.f);
    int e = rowptr[node], e1 = rowptr[node + 1];
    for (; e + 8 <= e1; e += 8) {
        int j0 = col[e + 0];
        int j1 = col[e + 1];
        int j2 = col[e + 2];
        int j3 = col[e + 3];
        int j4 = col[e + 4];
        int j5 = col[e + 5];
        int j6 = col[e + 6];
        int j7 = col[e + 7];
        float4 v0 = *(const float4*)&T[(size_t)j0 * HID + foff];
        float4 v1 = *(const float4*)&T[(size_t)j1 * HID + foff];
        float4 v2 = *(const float4*)&T[(size_t)j2 * HID + foff];
        float4 v3 = *(const float4*)&T[(size_t)j3 * HID + foff];
        float4 v4 = *(const float4*)&T[(size_t)j4 * HID + foff];
        float4 v5 = *(const float4*)&T[(size_t)j5 * HID + foff];
        float4 v6 = *(const float4*)&T[(size_t)j6 * HID + foff];
        float4 v7 = *(const float4*)&T[(size_t)j7 * HID + foff];
        acc.x  += (v0.x + v1.x) + (v2.x + v3.x);
        acc.y  += (v0.y + v1.y) + (v2.y + v3.y);
        acc.z  += (v0.z + v1.z) + (v2.z + v3.z);
        acc.w  += (v0.w + v1.w) + (v2.w + v3.w);
        acc2.x += (v4.x + v5.x) + (v6.x + v7.x);
        acc2.y += (v4.y + v5.y) + (v6.y + v7.y);
        acc2.z += (v4.z + v5.z) + (v6.z + v7.z);
        acc2.w += (v4.w + v5.w) + (v6.w + v7.w);
    }
    for (; e + 2 <= e1; e += 2) {
        int j0 = col[e + 0];
        int j1 = col[e + 1];
        float4 v0 = *(const float4*)&T[(size_t)j0 * HID + foff];
        float4 v1 = *(const float4*)&T[(size_t)j1 * HID + foff];
        acc.x  += v0.x; acc.y  += v0.y; acc.z  += v0.z; acc.w  += v0.w;
        acc2.x += v1.x; acc2.y += v1.y; acc2.z += v1.z; acc2.w += v1.w;
    }
    if (e < e1) {
        int j = col[e];
        float4 v = *(const float4*)&T[(size_t)j * HID + foff];
        acc.x += v.x; acc.y += v.y; acc.z += v.z; acc.w += v.w;
    }
    acc.x += acc2.x; acc.y += acc2.y; acc.z += acc2.z; acc.w += acc2.w;
    float d = dis[node];
    float4 bb = *(const float4*)&b[lane * 4];
    float4 o;
    o.x = fmaxf(fmaf(d, acc.x, bb.x), 0.0f);
    o.y = fmaxf(fmaf(d, acc.y, bb.y), 0.0f);
    o.z = fmaxf(fmaf(d, acc.z, bb.z), 0.0f);
    o.w = fmaxf(fmaf(d, acc.w, bb.w), 0.0f);
    *(float4*)&H[base] = o;
}

// out[i] = H[i,:] @ lin_w + lin_b    half-wave per node
__global__ __launch_bounds__(256) void k_final(const float* __restrict__ H,
                                               const float* __restrict__ w,
                                               const float* __restrict__ lb,
                                               float* __restrict__ out, int n) {
    int node = (blockIdx.x * 256 + threadIdx.x) >> 5;
    int lane = threadIdx.x & 31;
    if (node >= n) return;
    float4 h = *(const float4*)&H[(size_t)node * HID + lane * 4];
    float4 ww = *(const float4*)&w[lane * 4];
    float s = h.x * ww.x + h.y * ww.y + h.z * ww.z + h.w * ww.w;
    #pragma unroll
    for (int o = 16; o > 0; o >>= 1) s += __shfl_down(s, o, 64);  // stays within half
    if (lane == 0) out[node] = s + lb[0];
}

// ---------------- launch ----------------

extern "C" void kernel_launch(void* const* d_in, const int* in_sizes, int n_in,
                              void* d_out, int out_size, void* d_ws, size_t ws_size,
                              hipStream_t stream) {
    const float* x     = (const float*)d_in[0];
    const int*   ei    = (const int*)d_in[1];
    const float* Ws    = (const float*)d_in[2];
    const float* bs    = (const float*)d_in[3];
    const float* lin_w = (const float*)d_in[4];
    const float* lin_b = (const float*)d_in[5];
    float* out = (float*)d_out;

    int n = in_sizes[0] / HID;           // 50000
    int E = in_sizes[1] / 2;             // 600000
    int L = in_sizes[2] / (HID * HID);   // 7

    char* ws = (char*)d_ws;
    size_t off = 0;
    auto alloc = [&](size_t bytes) -> void* {
        void* p = ws + off;
        off += (bytes + 255) & ~(size_t)255;
        return p;
    };
    int*   deg     = (int*)alloc((size_t)n * 4);
    int*   cursor  = (int*)alloc((size_t)n * 4);
    int*   rowptr  = (int*)alloc((size_t)(n + 1) * 4);
    int*   partial = (int*)alloc(1024);
    float* dis     = (float*)alloc((size_t)n * 4);
    int*   col     = (int*)alloc((size_t)E * 4);
    float* hbuf    = (float*)alloc((size_t)n * HID * 4);
    float* tbuf    = (float*)alloc((size_t)n * HID * 4);
    (void)ws_size;

    hipMemsetAsync(deg, 0, (size_t)n * 4, stream);
    hipMemsetAsync(cursor, 0, (size_t)n * 4, stream);

    int eb = (E + 255) / 256;
    int nb = (n + 255) / 256;
    k_count<<<eb, 256, 0, stream>>>(ei, E, deg);
    k_scan1<<<nb, 256, 0, stream>>>(deg, rowptr, partial, n);
    k_scan2<<<1, 256, 0, stream>>>(partial, nb);
    k_scan3<<<nb, 256, 0, stream>>>(rowptr, partial, n, E);
    k_dis<<<nb, 256, 0, stream>>>(deg, dis, n);
    k_fill<<<eb, 256, 0, stream>>>(ei, E, rowptr, cursor, col);

    const float* hin = x;
    int gb = (n + BM - 1) / BM;  // 782 GEMM blocks
    int hb = (n + 7) / 8;        // 8 half-waves (=nodes) per 256-thread block
    for (int l = 0; l < L; ++l) {
        k_gemm<<<gb, 256, 0, stream>>>(hin, Ws + (size_t)l * HID * HID, dis, tbuf, n);
        k_agg<<<hb, 256, 0, stream>>>(tbuf, rowptr, col, dis, bs + (size_t)l * HID, hbuf, n);
        hin = hbuf;
    }
    k_final<<<hb, 256, 0, stream>>>(hbuf, lin_w, lin_b, out, n);
}